// Round 1
// baseline (169.330 us; speedup 1.0000x reference)
//
#include <hip/hip_runtime.h>

// inputs (256,128,64) f32, mask (256,128) i32, qparams (4,2,10) f32,
// W (4,256,10) f32, b (4,256) f32.
// out f32: outputs(256,128,256) ++ hx(128,256) ++ cx(128,256).
#define T_LEN 256
#define BATCH 128
#define NQ 10
#define HID 256
#define OUT_HX (T_LEN * BATCH * HID)
#define OUT_CX (OUT_HX + BATCH * HID)
#define ZSTRIDE 40   // floats per (b,t): 10 n, gate-minor float4

// ---------------- K1: circuit z precompute ----------------
// One thread per (t,g) instance. grid (128 b, 4 t-quarter) x 256 threads.
// Math identical to the validated phase-1 DP (r3/r4 bit-identical vs exact sim).
// Output layout gate-minor: zws[(b*256+t)*40 + n*4 + g] so K2 loads float4
// {g0,g1,g2,g3} per n.
__global__ __launch_bounds__(256) void zker(
    const float* __restrict__ inputs,
    const float* __restrict__ qparams,
    float* __restrict__ zws)
{
  const int b   = blockIdx.x;
  const int tq  = blockIdx.y;
  const int tid = threadIdx.x;
  const int t   = tq * 64 + (tid >> 2);
  const int g   = tid & 3;

  float th0[NQ], cth[NQ], sth[NQ];
#pragma unroll
  for (int k = 0; k < NQ; ++k) {
    th0[k]   = qparams[g * 2 * NQ + k];
    float t1 = qparams[g * 2 * NQ + NQ + k];
    sth[k] = __sinf(t1);
    cth[k] = __cosf(t1);
  }
  float cphi[NQ], sphi[NQ];
  const float* xp = inputs + (t * BATCH + b) * 64;
#pragma unroll
  for (int k = 0; k < NQ; ++k) {
    float ang = xp[k] + th0[k];
    sphi[k] = __sinf(ang);
    cphi[k] = __cosf(ang);
  }
  float* zout = zws + (b * T_LEN + t) * ZSTRIDE + g;
#pragma unroll
  for (int w = 0; w < NQ; ++w) {
    float vI, vZ, vY, vX; int js;
    if (w == NQ - 1) { vI = 0.f; vZ = cth[NQ-1]; vY = sth[NQ-1]; vX = 0.f; js = NQ - 2; }
    else             { vI = 1.f; vZ = 0.f; vY = 0.f; vX = 0.f; js = w; }
#pragma unroll
    for (int j = js; j >= 0; --j) {
      float nI = cth[j] * (cphi[j+1] * vZ - sphi[j+1] * vY);
      float nZ = cth[j] * vI;
      float nY = sth[j] * vX;
      float nX = -sth[j] * (sphi[j+1] * vZ + cphi[j+1] * vY);
      vI = nI; vZ = nZ; vY = nY; vX = nX;
    }
    zout[w * 4] = vI + cphi[0] * vZ - sphi[0] * vY;
  }
}

// ---------------- K2: all-gates-per-thread LSTM scan ----------------
// grid (128 b, 2 h-half) x 128 threads; thread owns one (b,h), all 4 gates.
// exp scales folded into W: sigmoid(x)=rcp(1+exp2(-log2e*x));
// tanh(x)=2*rcp(1+exp2(-2log2e*x))-1. Masks are binary so m*m==m lets us fuse
// i_m*g_m = m*ui*gb. z double-buffered in VGPRs via 2-step manual ping-pong
// (static indices only). The only serial-chain op per t is one FMA on c.
#define QSTEP(CUR, NXT, TT)                                              \
  {                                                                      \
    const int tnext = ((TT) + 1 < T_LEN) ? (TT) + 1 : T_LEN - 1;         \
    _Pragma("unroll")                                                    \
    for (int n = 0; n < NQ; ++n)                                         \
      NXT[n] = *(const float4*)(zpl + tnext * ZSTRIDE + n * 4);          \
    const float mN = mk[tnext];                                          \
    float p0 = bg[0], p1 = bg[1], p2 = bg[2], p3 = bg[3];                \
    _Pragma("unroll")                                                    \
    for (int n = 0; n < NQ; ++n) {                                       \
      p0 = fmaf(CUR[n].x, Wr[0][n], p0);                                 \
      p1 = fmaf(CUR[n].y, Wr[1][n], p1);                                 \
      p2 = fmaf(CUR[n].z, Wr[2][n], p2);                                 \
      p3 = fmaf(CUR[n].w, Wr[3][n], p3);                                 \
    }                                                                    \
    const float ef = __builtin_amdgcn_exp2f(p0);                         \
    const float ei = __builtin_amdgcn_exp2f(p1);                         \
    const float eg = __builtin_amdgcn_exp2f(p2);                         \
    const float eo = __builtin_amdgcn_exp2f(p3);                         \
    const float uf = __builtin_amdgcn_rcpf(1.f + ef);                    \
    const float ui = __builtin_amdgcn_rcpf(1.f + ei);                    \
    const float ug = __builtin_amdgcn_rcpf(1.f + eg);                    \
    const float uo = __builtin_amdgcn_rcpf(1.f + eo);                    \
    const float onem = 1.f - mcur;                                       \
    const float fm = fmaf(mcur, uf, onem);                               \
    const float gb = fmaf(2.f, ug, -1.f);                                \
    c = fmaf(fm, c, mcur * ui * gb);                                     \
    const float om = fmaf(mcur, uo, onem);                               \
    const float ec = __builtin_amdgcn_exp2f(c * KT2);                    \
    const float tcv = __builtin_amdgcn_rcpf(1.f + ec);                   \
    hv = om * fmaf(2.f, tcv, -1.f);                                      \
    out[(TT) * (BATCH * HID) + oidx] = hv;                               \
    mcur = mN;                                                           \
  }

__global__ __launch_bounds__(128) void scanker(
    const float* __restrict__ zws,
    const int*  __restrict__ mask,
    const float* __restrict__ W,
    const float* __restrict__ bias,
    float* __restrict__ out)
{
  const int b    = blockIdx.x;
  const int half = blockIdx.y;
  const int tid  = threadIdx.x;
  const int h    = half * 128 + tid;

  __shared__ float mk[T_LEN];
  for (int t = tid; t < T_LEN; t += 128) mk[t] = (float)mask[t * BATCH + b];
  __syncthreads();

  const float KS  = -1.44269504089f;  // -log2(e)
  const float KT2 = 2.f * KS;         // tanh scale

  float Wr[4][NQ]; float bg[4];
#pragma unroll
  for (int g = 0; g < 4; ++g) {
    const float s = (g == 2) ? KT2 : KS;
#pragma unroll
    for (int n = 0; n < NQ; ++n) Wr[g][n] = W[(g * HID + h) * NQ + n] * s;
    bg[g] = bias[g * HID + h] * s;
  }

  // launder a 0 through a VGPR so the z loads stay vector loads (keeps the
  // 80-float ping-pong in VGPRs instead of scalarizing into ~95 SGPRs)
  int vz; asm volatile("v_mov_b32 %0, 0" : "=v"(vz));
  const float* zpl = zws + b * T_LEN * ZSTRIDE + vz;

  float4 zA[NQ], zB[NQ];
#pragma unroll
  for (int n = 0; n < NQ; ++n) zA[n] = *(const float4*)(zpl + n * 4);
  float mcur = mk[0];

  float c = 0.f, hv = 0.f;
  const int oidx = b * HID + h;

  for (int t = 0; t < T_LEN; t += 2) {
    QSTEP(zA, zB, t);       // consume z[t], prefetch z[t+1]
    QSTEP(zB, zA, t + 1);   // consume z[t+1], prefetch z[t+2]
  }

  out[OUT_HX + oidx] = hv;
  out[OUT_CX + oidx] = c;
}

extern "C" void kernel_launch(void* const* d_in, const int* in_sizes, int n_in,
                              void* d_out, int out_size, void* d_ws, size_t ws_size,
                              hipStream_t stream)
{
  // identify arrays by unique element counts (order-proof)
  int ii = 0, im = 1, iq = 2, iw = 3, ib = 4;
  for (int i = 0; i < n_in; ++i) {
    switch (in_sizes[i]) {
      case 2097152: ii = i; break;   // inputs (256,128,64)
      case 32768:   im = i; break;   // mask (256,128)
      case 80:      iq = i; break;   // qparams (4,2,10)
      case 10240:   iw = i; break;   // W (4,256,10)
      case 1024:    ib = i; break;   // b (4,256)
      default: break;
    }
  }
  const float* inputs  = (const float*)d_in[ii];
  const int*   mask    = (const int*)d_in[im];
  const float* qparams = (const float*)d_in[iq];
  const float* W       = (const float*)d_in[iw];
  const float* bias    = (const float*)d_in[ib];
  float*       out     = (float*)d_out;
  float*       zws     = (float*)d_ws;   // needs 128*256*40*4 = 5.25 MB

  zker<<<dim3(BATCH, 4), dim3(256), 0, stream>>>(inputs, qparams, zws);
  scanker<<<dim3(BATCH, 2), dim3(128), 0, stream>>>(zws, mask, W, bias, out);
}

// Round 2
// 108.263 us; speedup vs baseline: 1.5641x; 1.5641x over previous
//
#include <hip/hip_runtime.h>

// inputs (256,128,64) f32, mask (256,128) i32, qparams (4,2,10) f32,
// W (4,256,10) f32, b (4,256) f32.
// out f32: outputs(256,128,256) ++ hx(128,256) ++ cx(128,256).
#define T_LEN 256
#define BATCH 128
#define NQ 10
#define HID 256
#define OUT_HX (T_LEN * BATCH * HID)
#define OUT_CX (OUT_HX + BATCH * HID)
#define ZSTRIDE 40   // global z floats per (b,t): 10 n, gate-minor float4
#define ZROW 44      // padded LDS row stride (dwords) -> 8 lanes/bank-group on b128
#define TROW 65      // h-tile row stride (odd -> conflict-free b32 both phases)

#define KS  (-1.44269504089f)   // -log2(e): sigmoid scale
#define KT2 (-2.88539008178f)   // -2*log2(e): tanh scale

// ---------------- K1: circuit z precompute ----------------
// One thread per (t,g). Math identical to the validated analytic DP.
// Gate exp2-scale folded into z here (sigmoid gates *KS, tanh gate *KT2);
// scanker scales bias to match, W stays raw.
__global__ __launch_bounds__(256) void zker(
    const float* __restrict__ inputs,
    const float* __restrict__ qparams,
    float* __restrict__ zws)
{
  const int b   = blockIdx.x;
  const int tq  = blockIdx.y;
  const int tid = threadIdx.x;
  const int t   = tq * 64 + (tid >> 2);
  const int g   = tid & 3;

  const float sg = (g == 2) ? KT2 : KS;

  float th0[NQ], cth[NQ], sth[NQ];
#pragma unroll
  for (int k = 0; k < NQ; ++k) {
    th0[k]   = qparams[g * 2 * NQ + k];
    float t1 = qparams[g * 2 * NQ + NQ + k];
    sth[k] = __sinf(t1);
    cth[k] = __cosf(t1);
  }
  float cphi[NQ], sphi[NQ];
  const float* xp = inputs + (t * BATCH + b) * 64;
#pragma unroll
  for (int k = 0; k < NQ; ++k) {
    float ang = xp[k] + th0[k];
    sphi[k] = __sinf(ang);
    cphi[k] = __cosf(ang);
  }
  float* zout = zws + (b * T_LEN + t) * ZSTRIDE + g;
#pragma unroll
  for (int w = 0; w < NQ; ++w) {
    float vI, vZ, vY, vX; int js;
    if (w == NQ - 1) { vI = 0.f; vZ = cth[NQ-1]; vY = sth[NQ-1]; vX = 0.f; js = NQ - 2; }
    else             { vI = 1.f; vZ = 0.f; vY = 0.f; vX = 0.f; js = w; }
#pragma unroll
    for (int j = js; j >= 0; --j) {
      float nI = cth[j] * (cphi[j+1] * vZ - sphi[j+1] * vY);
      float nZ = cth[j] * vI;
      float nY = sth[j] * vX;
      float nX = -sth[j] * (sphi[j+1] * vZ + cphi[j+1] * vY);
      vI = nI; vZ = nZ; vY = nY; vX = nX;
    }
    zout[w * 4] = (vI + cphi[0] * vZ - sphi[0] * vY) * sg;
  }
}

// ---------------- K2: parallel-scan LSTM ----------------
// c_t = fm_t*c_{t-1} + w_t is a linear recurrence with h-independent-of-c
// coefficients -> associative scan over t. Block = (b, 64-h group), 8 waves,
// wave owns 8 h. Round r: lane = t = r*64+lane; z row read once from LDS and
// reused for all 8 h; W/bias wave-uniform (readfirstlane) -> SGPR scalar
// loads. 6-step shfl_up Hillis-Steele scan per (h, round); carry via lane 63.
// h-values transposed through padded LDS tile -> coalesced 256B stores.
__global__ __launch_bounds__(512) void scanker(
    const float* __restrict__ zws,
    const int*  __restrict__ mask,
    const float* __restrict__ W,
    const float* __restrict__ bias,
    float* __restrict__ out)
{
  const int b    = blockIdx.x;      // 0..127
  const int h0   = blockIdx.y * 64; // h-group base
  const int tid  = threadIdx.x;     // 0..511
  const int lane = tid & 63;
  const int wavu = __builtin_amdgcn_readfirstlane(tid >> 6);  // provably uniform

  __shared__ float zlds[T_LEN * ZROW];   // 45056 B
  __shared__ float tlds[64 * TROW];      // 16640 B
  __shared__ float mk[T_LEN];            //  1024 B

  // stage z[b] (40KB) with padding; coalesced global float4 reads
  {
    const float4* zg = (const float4*)(zws + b * T_LEN * ZSTRIDE);
    for (int i = tid; i < T_LEN * 10; i += 512) {
      int t = i / 10, c4 = i - t * 10;
      *(float4*)&zlds[t * ZROW + c4 * 4] = zg[i];
    }
  }
  for (int t = tid; t < T_LEN; t += 512) mk[t] = (float)mask[t * BATCH + b];
  __syncthreads();

  float carry[8];
#pragma unroll
  for (int i = 0; i < 8; ++i) carry[i] = 0.f;

  for (int r = 0; r < 4; ++r) {
    const int t = r * 64 + lane;
    float4 z4[10];
#pragma unroll
    for (int n = 0; n < NQ; ++n) z4[n] = *(const float4*)&zlds[t * ZROW + n * 4];
    const float m = mk[t];
    const float onem = 1.f - m;

#pragma unroll
    for (int hh = 0; hh < 8; ++hh) {
      const int h = h0 + wavu * 8 + hh;
      const int wb = __builtin_amdgcn_readfirstlane(h * NQ);  // uniform W row base

      float p0 = bias[0 * HID + h] * KS;
      float p1 = bias[1 * HID + h] * KS;
      float p2 = bias[2 * HID + h] * KT2;
      float p3 = bias[3 * HID + h] * KS;
#pragma unroll
      for (int n = 0; n < NQ; ++n) {
        p0 = fmaf(z4[n].x, W[0 * HID * NQ + wb + n], p0);
        p1 = fmaf(z4[n].y, W[1 * HID * NQ + wb + n], p1);
        p2 = fmaf(z4[n].z, W[2 * HID * NQ + wb + n], p2);
        p3 = fmaf(z4[n].w, W[3 * HID * NQ + wb + n], p3);
      }
      const float uf = __builtin_amdgcn_rcpf(1.f + __builtin_amdgcn_exp2f(p0));
      const float ui = __builtin_amdgcn_rcpf(1.f + __builtin_amdgcn_exp2f(p1));
      const float ug = __builtin_amdgcn_rcpf(1.f + __builtin_amdgcn_exp2f(p2));
      const float uo = __builtin_amdgcn_rcpf(1.f + __builtin_amdgcn_exp2f(p3));

      const float fm = fmaf(m, uf, onem);          // decay a_t
      const float gb = fmaf(2.f, ug, -1.f);        // tanh(pre_g)
      float wt = m * ui * gb;                      // input w_t (m*m==m)
      const float om = fmaf(m, uo, onem);

      // inclusive Hillis-Steele scan of affine ops (a,w) over 64 t-lanes
      float a = fm, wv = wt;
#pragma unroll
      for (int d = 1; d < 64; d <<= 1) {
        float au = __shfl_up(a, d, 64);
        float wu = __shfl_up(wv, d, 64);
        const bool p = (lane >= d);
        au = p ? au : 1.f;
        wu = p ? wu : 0.f;
        wv = fmaf(a, wu, wv);
        a  = a * au;
      }
      const float ct = fmaf(a, carry[hh], wv);
      carry[hh] = __shfl(ct, 63, 64);

      const float ec = __builtin_amdgcn_exp2f(ct * KT2);
      const float tc = fmaf(2.f, __builtin_amdgcn_rcpf(1.f + ec), -1.f);
      const float hv = om * tc;

      tlds[lane * TROW + wavu * 8 + hh] = hv;

      if (r == 3 && lane == 63) {
        out[OUT_HX + b * HID + h] = hv;
        out[OUT_CX + b * HID + h] = ct;
      }
    }
    __syncthreads();
    // coalesced writeout: 64 t x 64 h tile, 256B contiguous per t
#pragma unroll
    for (int s = 0; s < 2; ++s) {
      const int q = tid + s * 512;          // 0..1023
      const int tt = q >> 4, c = q & 15;
      float4 v;
      v.x = tlds[tt * TROW + 4 * c + 0];
      v.y = tlds[tt * TROW + 4 * c + 1];
      v.z = tlds[tt * TROW + 4 * c + 2];
      v.w = tlds[tt * TROW + 4 * c + 3];
      *(float4*)&out[(r * 64 + tt) * (BATCH * HID) + b * HID + h0 + 4 * c] = v;
    }
    __syncthreads();
  }
}

extern "C" void kernel_launch(void* const* d_in, const int* in_sizes, int n_in,
                              void* d_out, int out_size, void* d_ws, size_t ws_size,
                              hipStream_t stream)
{
  // identify arrays by unique element counts (order-proof)
  int ii = 0, im = 1, iq = 2, iw = 3, ib = 4;
  for (int i = 0; i < n_in; ++i) {
    switch (in_sizes[i]) {
      case 2097152: ii = i; break;   // inputs (256,128,64)
      case 32768:   im = i; break;   // mask (256,128)
      case 80:      iq = i; break;   // qparams (4,2,10)
      case 10240:   iw = i; break;   // W (4,256,10)
      case 1024:    ib = i; break;   // b (4,256)
      default: break;
    }
  }
  const float* inputs  = (const float*)d_in[ii];
  const int*   mask    = (const int*)d_in[im];
  const float* qparams = (const float*)d_in[iq];
  const float* W       = (const float*)d_in[iw];
  const float* bias    = (const float*)d_in[ib];
  float*       out     = (float*)d_out;
  float*       zws     = (float*)d_ws;   // needs 128*256*40*4 = 5.25 MB

  zker<<<dim3(BATCH, 4), dim3(256), 0, stream>>>(inputs, qparams, zws);
  scanker<<<dim3(BATCH, 4), dim3(512), 0, stream>>>(zws, mask, W, bias, out);
}